// Round 1
// 119.549 us; speedup vs baseline: 1.0113x; 1.0113x over previous
//
#include <hip/hip_runtime.h>
#include <stdint.h>

// Problem constants
#define NUM_C 1000
#define NB    4096
#define NCOL  9192          // NB + NUM_C + NO
#define NPAD  9216          // 288 row-tiles of 32
#define DK    512
#define BM    128
#define BN    256
#define INV_T 10.0f

typedef __attribute__((ext_vector_type(16))) float f32x16;
typedef __attribute__((ext_vector_type(8)))  int   i32x8;

// workspace layout (bytes)
// fall: MX fragment layout [tile=288][kq=8][chunk16B=128(swizzled)] = 4,718,592 B
//   lane l of a tile holds row (l&31), k = kq*64 + (l>>5)*32 + [0..31]
//   chunk swizzle within each 2048B kq-slab: phys p = c ^ ((c>>3)&7)  (involution)
#define OFF_FALL  0u
#define OFF_CNT   4718592u           // uint[1024] final hist (targets+pseudo)
#define OFF_CNTT  4722688u           // uint[1024] final hist (targets only)
#define OFF_S     4726784u           // float[4096]
#define OFF_P     4743168u           // float[4096]  (contiguous after S)

__device__ __forceinline__ void async16(const void* g, void* l) {
  __builtin_amdgcn_global_load_lds((const __attribute__((address_space(1))) void*)g,
                                   (__attribute__((address_space(3))) void*)l,
                                   16, 0, 0);
}

// f32 -> e4m3fn (OCP), software RNE fallback
__device__ __forceinline__ unsigned sw_e4m3(float x) {
  float ax = fabsf(x);
  unsigned s = (__float_as_uint(x) >> 24) & 0x80u;
  if (ax < 0.015625f) {
    int n = (int)rintf(ax * 512.0f);
    if (n >= 8) return s | 0x08u;
    return s | (unsigned)n;
  }
  if (ax >= 448.0f) return s | 0x7Eu;
  unsigned u = __float_as_uint(ax);
  int ee = (int)(u >> 23) - 127;
  float scale = __uint_as_float((unsigned)(3 - ee + 127) << 23);
  int qv = (int)rintf(ax * scale);
  if (qv == 16) { ee++; qv = 8; }
  return s | (unsigned)(((ee + 7) << 3) | (qv - 8));
}

template <bool HI>
__device__ __forceinline__ int cvt2(float a, float b, int old) {
#if __has_builtin(__builtin_amdgcn_cvt_pk_fp8_f32)
  return __builtin_amdgcn_cvt_pk_fp8_f32(a, b, old, HI);
#else
  unsigned pk = sw_e4m3(a) | (sw_e4m3(b) << 8);
  return HI ? (int)(((unsigned)old & 0x0000FFFFu) | (pk << 16))
            : (int)(((unsigned)old & 0xFFFF0000u) | pk);
#endif
}

__device__ __forceinline__ i32x8 mk8(uint4 lo, uint4 hi) {
  i32x8 r;
  r[0] = (int)lo.x; r[1] = (int)lo.y; r[2] = (int)lo.z; r[3] = (int)lo.w;
  r[4] = (int)hi.x; r[5] = (int)hi.y; r[6] = (int)hi.z; r[7] = (int)hi.w;
  return r;
}

// MX-scaled fp8 MFMA, unit scales (e8m0 127 = 1.0): same products as plain fp8
#define MFMA_SC(a, b, c) \
  __builtin_amdgcn_mfma_scale_f32_32x32x64_f8f6f4((a), (b), (c), 0, 0, 0, 0x7F7F7F7F, 0, 0x7F7F7F7F)

// Build fall in swizzled MX fragment layout: one thread = one 16B chunk.
// blocks 0..15: LDS partial histograms -> global atomicAdd into cnt/cntT (pre-zeroed)
// blocks 16..47: zero S/P
__global__ __launch_bounds__(256) void prep_k(const float* __restrict__ centers,
                                              const float* __restrict__ feats,
                                              const float* __restrict__ ood,
                                              const int* __restrict__ targets,
                                              const int* __restrict__ pseudo,
                                              uint4* __restrict__ fall,
                                              unsigned* __restrict__ cnt,
                                              unsigned* __restrict__ cntT,
                                              float* __restrict__ SP) {
  __shared__ unsigned hc[1024];
  __shared__ unsigned hct[1024];
  const int tid = threadIdx.x;

  int idx  = blockIdx.x * 256 + tid;      // 0 .. 294911 (16B chunks)
  int tile = idx >> 10;                   // 1024 chunks per 32-row tile
  int kq   = (idx >> 7) & 7;              // 128 chunks per kq-slab
  int p    = idx & 127;                   // physical chunk in slab
  int c    = p ^ ((p >> 3) & 7);          // logical chunk (involution)
  int lane = c >> 1;
  int row  = tile * 32 + (lane & 31);
  int k0   = kq * 64 + (lane >> 5) * 32 + (c & 1) * 16;

  const float* src = nullptr;
  if (row < NB)              src = feats   + (size_t)row * DK;
  else if (row < NB + NUM_C) src = centers + (size_t)(row - NB) * DK;
  else if (row < NCOL)       src = ood     + (size_t)(row - NB - NUM_C) * DK;
  uint4 out = make_uint4(0u, 0u, 0u, 0u);
  if (src) {
    float4 v0 = *(const float4*)(src + k0);
    float4 v1 = *(const float4*)(src + k0 + 4);
    float4 v2 = *(const float4*)(src + k0 + 8);
    float4 v3 = *(const float4*)(src + k0 + 12);
    int q;
    q = 0; q = cvt2<false>(v0.x, v0.y, q); q = cvt2<true>(v0.z, v0.w, q); out.x = (unsigned)q;
    q = 0; q = cvt2<false>(v1.x, v1.y, q); q = cvt2<true>(v1.z, v1.w, q); out.y = (unsigned)q;
    q = 0; q = cvt2<false>(v2.x, v2.y, q); q = cvt2<true>(v2.z, v2.w, q); out.z = (unsigned)q;
    q = 0; q = cvt2<false>(v3.x, v3.y, q); q = cvt2<true>(v3.z, v3.w, q); out.w = (unsigned)q;
  }
  fall[idx] = out;

  if (blockIdx.x < 16) {
    for (int kk = tid; kk < 1024; kk += 256) { hc[kk] = 0u; hct[kk] = 0u; }
    __syncthreads();
    int i = blockIdx.x * 256 + tid;      // 0..4095
    int tt = targets[i];
    atomicAdd(&hc[tt], 1u);
    atomicAdd(&hct[tt], 1u);
    atomicAdd(&hc[pseudo[i]], 1u);
    __syncthreads();
    for (int kk = tid; kk < 1024; kk += 256) {
      unsigned cc = hc[kk], ct = hct[kk];
      if (cc) atomicAdd(&cnt[kk], cc);   // device-scope by default
      if (ct) atomicAdd(&cntT[kk], ct);
    }
  } else if (blockIdx.x < 48) {
    SP[(blockIdx.x - 16) * 256 + tid] = 0.0f;   // zeros S[4096] then P[4096]
  }
}

// Fused MX-fp8 GEMM 128x256 with 32x32x64 scaled MFMA (unit scales).
// A tile (64 KB) resident in LDS (one prologue DMA, linear dest; content was
// pre-swizzled at the source by prep -> swizzled reads are conflict-free).
// B direct from global, ping-pong prefetch; each wave owns a 64-col quarter
// (no B redundancy within block). Zero barriers in the K-loop.
__global__ __launch_bounds__(256, 2) void gemm_fused(const unsigned char* __restrict__ fall,
                                                     const int* __restrict__ targets,
                                                     const int* __restrict__ pseudo,
                                                     const unsigned* __restrict__ cnt,
                                                     float* __restrict__ Sacc,
                                                     float* __restrict__ Pacc) {
  __shared__ unsigned char Alds[65536];   // 4 row-tiles of 32 (128 rows x 512 k)
  __shared__ int    sLbl[BN];
  __shared__ float  sRw0[BN];
  __shared__ float  sRw1[BN];
  __shared__ int    sTgt[BM];

  const int tid  = threadIdx.x;
  // chunked XCD swizzle (1152 = 8*144, bijective): nTile-major chunks ->
  // per-XCD working set ~4.5 col-supertiles (576 KB B) + full A (2 MB) < 4 MiB L2
  int flat = (int)blockIdx.y * 36 + (int)blockIdx.x;
  int swz  = (flat & 7) * 144 + (flat >> 3);
  const int nTile = swz >> 5;     // 0..35
  const int mTile = swz & 31;     // 0..31
  const int lane  = tid & 63;
  const int wv    = tid >> 6;     // wave 0..3 = column quarter

  // prologue: copy A (contiguous 64 KB of fall) into LDS via DMA (linear dest)
  {
    const unsigned char* aSrc = fall + (size_t)mTile * 65536;
#pragma unroll
    for (int i = 0; i < 16; i++)
      async16(aSrc + (i * 256 + tid) * 16, &Alds[(i * 256 + tid) * 16]);
  }

  // per-column tables (lbl, 1/w, 1/(w-1)); per-row targets. w = 1 + cnt[tac].
  {
    int j = nTile * BN + tid;
    int lbl, tac;
    if (j >= NCOL)         { lbl = -1; tac = -1; }
    else if (j < NB)       { tac = targets[j]; lbl = tac; }
    else if (j < NB+NUM_C) { tac = j - NB;     lbl = tac; }
    else                   { tac = pseudo[j - NB - NUM_C]; lbl = NUM_C; }
    sLbl[tid] = lbl;
    if (tac >= 0) {
      float w = (float)(1u + cnt[tac]);
      sRw0[tid] = 1.0f / w;
      sRw1[tid] = 1.0f / (w - 1.0f);  // only selected when a positive exists => w>=2
    } else {
      sRw0[tid] = 0.f;
      sRw1[tid] = 0.f;
    }
    if (tid < BM) sTgt[tid] = targets[mTile * BM + tid];
  }

  f32x16 acc[4][2];
  {
    f32x16 z;
#pragma unroll
    for (int t = 0; t < 16; t++) z[t] = 0.f;
#pragma unroll
    for (int mi = 0; mi < 4; mi++) { acc[mi][0] = z; acc[mi][1] = z; }
  }

  // swizzled per-lane chunk offsets within a 2048B kq-slab:
  // logical chunks c0=2*lane, c1=2*lane+1 -> phys offsets off0, off0^16
  const int swzo = ((lane >> 2) & 7) << 4;
  const int off0 = (lane << 5) ^ swzo;
  const int off1 = off0 ^ 16;

  const unsigned char* bBase0 = fall + (size_t)(nTile * 8 + wv * 2) * 16384;
  const unsigned char* bBase1 = bBase0 + 16384;

  uint4 b0l = *(const uint4*)(bBase0 + off0);
  uint4 b0h = *(const uint4*)(bBase0 + off1);
  uint4 b1l = *(const uint4*)(bBase1 + off0);
  uint4 b1h = *(const uint4*)(bBase1 + off1);

  __syncthreads();   // A landed (vmcnt drain) + tables ready; only barrier

#pragma unroll
  for (int kq = 0; kq < 8; kq++) {
    uint4 n0l, n0h, n1l, n1h;
    if (kq < 7) {
      const unsigned char* pb0 = bBase0 + (kq + 1) * 2048;
      const unsigned char* pb1 = bBase1 + (kq + 1) * 2048;
      n0l = *(const uint4*)(pb0 + off0); n0h = *(const uint4*)(pb0 + off1);
      n1l = *(const uint4*)(pb1 + off0); n1h = *(const uint4*)(pb1 + off1);
    }
    i32x8 bf0 = mk8(b0l, b0h);
    i32x8 bf1 = mk8(b1l, b1h);
#pragma unroll
    for (int mi = 0; mi < 4; mi++) {
      const unsigned ao = (unsigned)mi * 16384u + (unsigned)kq * 2048u;
      uint4 al = *(const uint4*)&Alds[ao + off0];
      uint4 ah = *(const uint4*)&Alds[ao + off1];
      i32x8 af = mk8(al, ah);
      acc[mi][0] = MFMA_SC(af, bf0, acc[mi][0]);
      acc[mi][1] = MFMA_SC(af, bf1, acc[mi][1]);
    }
    if (kq < 7) { b0l = n0l; b0h = n0h; b1l = n1l; b1h = n1h; }
  }

  // Epilogue: 32x32 C layout: col = lane&31, row = (reg&3) + 8*(reg>>2) + 4*(lane>>5)
  // l = acc*10; S += exp(l-10) * (diag?0 : pos?1/(w-1) : 1/w); P += pos?l:0
  const int cq = lane & 31;
  const int hh = lane >> 5;
  const int jl0 = wv * 64 + cq;
  const int jl1 = jl0 + 32;
  const int jg0 = nTile * BN + jl0;
  const int jg1 = jg0 + 32;
  const int lbl0 = sLbl[jl0], lbl1 = sLbl[jl1];
  const float w00 = sRw0[jl0], w01 = sRw1[jl0];
  const float w10 = sRw0[jl1], w11 = sRw1[jl1];

#define RED(m, s, h)                                           \
  {                                                            \
    float sS = (lane & (m)) ? vS[(s)] : vS[(s) + (h)];         \
    float sP = (lane & (m)) ? vP[(s)] : vP[(s) + (h)];         \
    float rS = __shfl_xor(sS, (m), 64);                        \
    float rP = __shfl_xor(sP, (m), 64);                        \
    vS[(s)] = ((lane & (m)) ? vS[(s) + (h)] : vS[(s)]) + rS;   \
    vP[(s)] = ((lane & (m)) ? vP[(s) + (h)] : vP[(s)]) + rP;   \
  }

#pragma unroll
  for (int mi = 0; mi < 4; mi++) {
    float vS[16], vP[16];
#pragma unroll
    for (int r = 0; r < 16; r++) {
      int rowT = (r & 3) + 8 * (r >> 2) + 4 * hh;
      int iloc = mi * 32 + rowT;
      int ig   = mTile * BM + iloc;
      int ti   = sTgt[iloc];
      float l0 = acc[mi][0][r] * INV_T;
      float l1 = acc[mi][1][r] * INV_T;
      bool d0 = (jg0 == ig), d1 = (jg1 == ig);
      bool p0 = (lbl0 == ti) && !d0;
      bool p1 = (lbl1 == ti) && !d1;
      float r0 = d0 ? 0.f : (p0 ? w01 : w00);
      float r1 = d1 ? 0.f : (p1 ? w11 : w10);
      vS[r] = __expf(l0 - 10.0f) * r0 + __expf(l1 - 10.0f) * r1;
      vP[r] = (p0 ? l0 : 0.f) + (p1 ? l1 : 0.f);
    }
    // value-halving butterfly over the 32 lanes of each half (cols), 16 regs -> 1
    RED(1, 0, 8) RED(1, 1, 8) RED(1, 2, 8) RED(1, 3, 8)
    RED(1, 4, 8) RED(1, 5, 8) RED(1, 6, 8) RED(1, 7, 8)
    RED(2, 0, 4) RED(2, 1, 4) RED(2, 2, 4) RED(2, 3, 4)
    RED(4, 0, 2) RED(4, 1, 2)
    RED(8, 0, 1)
    vS[0] += __shfl_xor(vS[0], 16, 64);
    vP[0] += __shfl_xor(vP[0], 16, 64);
    if (!(lane & 16)) {
      int rr   = ((lane & 1) << 3) | ((lane & 2) << 1) | ((lane & 4) >> 1) | ((lane & 8) >> 3);
      int rowT = (rr & 3) + 8 * (rr >> 2) + 4 * hh;
      int ig   = mTile * BM + mi * 32 + rowT;
      atomicAdd(&Sacc[ig], vS[0]);
      atomicAdd(&Pacc[ig], vP[0]);
    }
  }
#undef RED
}

// loss = -mean( P/npos - 10 - log S );  npos_i = cntT[targets[i]]
__global__ __launch_bounds__(256) void finalize_k(const float* __restrict__ S,
                                                  const float* __restrict__ P,
                                                  const int* __restrict__ targets,
                                                  const unsigned* __restrict__ cntT,
                                                  float* __restrict__ out) {
  __shared__ unsigned ct[1024];
  __shared__ float red[4];
  int tid = threadIdx.x;
  for (int k = tid; k < 1024; k += 256) ct[k] = cntT[k];
  __syncthreads();
  float local = 0.f;
  for (int i = tid; i < NB; i += 256) {
    float npos = (float)ct[targets[i]];
    local += P[i] / npos - INV_T - __logf(S[i]);
  }
  for (int m = 1; m < 64; m <<= 1) local += __shfl_xor(local, m, 64);
  if ((tid & 63) == 0) red[tid >> 6] = local;
  __syncthreads();
  if (tid == 0) {
    float t = red[0] + red[1] + red[2] + red[3];
    out[0] = -t / (float)NB;
  }
}

extern "C" void kernel_launch(void* const* d_in, const int* in_sizes, int n_in,
                              void* d_out, int out_size, void* d_ws, size_t ws_size,
                              hipStream_t stream) {
  const float* centers = (const float*)d_in[0];   // [1000][512] f32
  const float* feats   = (const float*)d_in[1];   // [4096][512] f32
  const int*   targets = (const int*)d_in[2];     // [4096] i32
  const float* ood     = (const float*)d_in[3];   // [4096][512] f32
  const int*   pseudo  = (const int*)d_in[4];     // [4096] i32

  char* ws = (char*)d_ws;
  uint4*    fall  = (uint4*)(ws + OFF_FALL);
  unsigned* cnt   = (unsigned*)(ws + OFF_CNT);
  unsigned* cntT  = (unsigned*)(ws + OFF_CNTT);
  float*    Sacc  = (float*)(ws + OFF_S);
  float*    Pacc  = (float*)(ws + OFF_P);

  hipMemsetAsync(ws + OFF_CNT, 0, 8192, stream);   // zero cnt + cntT
  prep_k<<<dim3((NPAD * 32) / 256), 256, 0, stream>>>(centers, feats, ood, targets, pseudo,
                                                      fall, cnt, cntT, Sacc);
  gemm_fused<<<dim3(NPAD / BN, NB / BM), 256, 0, stream>>>((const unsigned char*)fall, targets,
                                                           pseudo, cnt, Sacc, Pacc);
  finalize_k<<<1, 256, 0, stream>>>(Sacc, Pacc, targets, cntT, (float*)d_out);
}